// Round 3
// baseline (480.098 us; speedup 1.0000x reference)
//
#include <hip/hip_runtime.h>

// B=512, D=1024, H1=512, H2=128
// Outputs (f32, concat): recover [512,1024], c2 [512,128], Jac [512,128,1024]
//
// Pipeline (all GEMMs on matrix cores):
//  prep: W1T f16 [1024][512]; W2h f16; W2T_h f16 [512][128];
//        W1s [512][3072]=[wh|wl|wh]; xs [512][3072]=[xh|xh|xl]; W2s [128][1536]=[w2h|w2l|w2h]
//  sgemm<0>: c1 = sigmoid(xs@W1s^T+b1)  (3-term split-f16 == fp32 fidelity)
//            -> c1s [512][1536]=[c1h|c1h|c1l], s1p
//  sgemm<1>: c2 = sigmoid(c1s@W2s^T+b2) -> out_c2, s2p, c2h
//  sgemm<2>: c3h = f16(sigmoid(c2h@W2T_h^T+b3))   (plain f16, loose threshold)
//  mfma_bt<bias>: recover = c3@W1 + b_r -> out
//  build_A: A_all[b][h][k] = f16(s2p[b][h]*W2[h][k]*s1p[b][k])
//  jac256:  Jac[2b:2b+2] = A_all[2b:2b+2] @ W1T^T   (256x128 tile, 2 batches/block)

typedef _Float16 f16x8 __attribute__((ext_vector_type(8)));
typedef _Float16 f16x4 __attribute__((ext_vector_type(4)));
typedef float    f32x4 __attribute__((ext_vector_type(4)));

__device__ __forceinline__ void gld_lds16(const _Float16* src, _Float16* dst_wave_uniform) {
    // async global->LDS, 16B per lane; LDS dest = wave-uniform base + lane*16
    __builtin_amdgcn_global_load_lds((const __attribute__((address_space(1))) unsigned int*)src,
                                     (__attribute__((address_space(3))) unsigned int*)dst_wave_uniform,
                                     16, 0, 0);
}

// ---------------- prep ----------------
__global__ __launch_bounds__(256) void prep_kernel(const float* __restrict__ W1,
                                                   const float* __restrict__ W2,
                                                   const float* __restrict__ x,
                                                   _Float16* __restrict__ W1T,    // [1024][512]
                                                   _Float16* __restrict__ W2h,    // [128][512]
                                                   _Float16* __restrict__ W2T_h,  // [512][128]
                                                   _Float16* __restrict__ W1s,    // [512][3072]
                                                   _Float16* __restrict__ xs,     // [512][3072]
                                                   _Float16* __restrict__ W2s) {  // [128][1536]
    int bx = blockIdx.x, tid = threadIdx.x;
    if (bx < 512) {
        __shared__ float tile[32][33];
        int dt = (bx & 31) * 32, kt = (bx >> 5) * 32;
        int tx = tid & 31, ty = tid >> 5;  // 32 x 8
        #pragma unroll
        for (int r = 0; r < 32; r += 8)
            tile[ty + r][tx] = W1[(kt + ty + r) * 1024 + dt + tx];
        __syncthreads();
        #pragma unroll
        for (int r = 0; r < 32; r += 8)
            W1T[(size_t)(dt + ty + r) * 512 + kt + tx] = (_Float16)tile[tx][ty + r];
    } else if (bx < 576) {
        int i = (bx - 512) * 1024 + tid * 4;
        f32x4 v = *(const f32x4*)(W2 + i);
        f16x4 h;
        h.x = (_Float16)v.x; h.y = (_Float16)v.y; h.z = (_Float16)v.z; h.w = (_Float16)v.w;
        *(f16x4*)(W2h + i) = h;
    } else if (bx < 640) {
        // W2T_h[n][k] = f16(W2[k][n]); tiles over (k:128)x(n:512)
        __shared__ float tile[32][33];
        int t = bx - 576;
        int kt = (t & 3) * 32, nt = (t >> 2) * 32;
        int tx = tid & 31, ty = tid >> 5;
        #pragma unroll
        for (int r = 0; r < 32; r += 8)
            tile[ty + r][tx] = W2[(kt + ty + r) * 512 + nt + tx];
        __syncthreads();
        #pragma unroll
        for (int r = 0; r < 32; r += 8)
            W2T_h[(size_t)(nt + ty + r) * 128 + kt + tx] = (_Float16)tile[tx][ty + r];
    } else if (bx < 1152) {
        // W1s row t: [wh | wl | wh]
        int t = bx - 640, col = tid * 4;
        f32x4 v = *(const f32x4*)(W1 + (size_t)t * 1024 + col);
        f16x4 h, l;
        #pragma unroll
        for (int i = 0; i < 4; ++i) { h[i] = (_Float16)v[i]; l[i] = (_Float16)(v[i] - (float)h[i]); }
        _Float16* row = W1s + (size_t)t * 3072;
        *(f16x4*)(row + col) = h;
        *(f16x4*)(row + 1024 + col) = l;
        *(f16x4*)(row + 2048 + col) = h;
    } else if (bx < 1664) {
        // xs row t: [xh | xh | xl]
        int t = bx - 1152, col = tid * 4;
        f32x4 v = *(const f32x4*)(x + (size_t)t * 1024 + col);
        f16x4 h, l;
        #pragma unroll
        for (int i = 0; i < 4; ++i) { h[i] = (_Float16)v[i]; l[i] = (_Float16)(v[i] - (float)h[i]); }
        _Float16* row = xs + (size_t)t * 3072;
        *(f16x4*)(row + col) = h;
        *(f16x4*)(row + 1024 + col) = h;
        *(f16x4*)(row + 2048 + col) = l;
    } else {
        // W2s row: [w2h | w2l | w2h]
        int t = bx - 1664;
        int row = t * 2 + (tid >> 7), col = (tid & 127) * 4;
        f32x4 v = *(const f32x4*)(W2 + (size_t)row * 512 + col);
        f16x4 h, l;
        #pragma unroll
        for (int i = 0; i < 4; ++i) { h[i] = (_Float16)v[i]; l[i] = (_Float16)(v[i] - (float)h[i]); }
        _Float16* orow = W2s + (size_t)row * 1536;
        *(f16x4*)(orow + col) = h;
        *(f16x4*)(orow + 512 + col) = l;
        *(f16x4*)(orow + 1024 + col) = h;
    }
}

// ---------------- small MFMA GEMM: 1 wave, 32x32 tile, Out=sig(A@B^T+bias) ----------------
// A [M][K], B [N][K] f16 row-major, stride == K. K % 64 == 0.
// EPI 0 (g1): o3=c1s (stride 1536, [h|h|l]), o2=s1p (512)
// EPI 1 (g2): o1=out_c2 (128), o2=s2p (128), o3=c2h (128)
// EPI 2 (g3): o3=c3h (512)
template <int EPI>
__global__ __launch_bounds__(64) void sgemm(const _Float16* __restrict__ A,
                                            const _Float16* __restrict__ B,
                                            const float* __restrict__ bias,
                                            int K,
                                            float* __restrict__ o1,
                                            float* __restrict__ o2,
                                            _Float16* __restrict__ o3) {
    __shared__ __align__(16) _Float16 As[32 * 64];
    __shared__ __align__(16) _Float16 Bs[32 * 64];
    const int m0 = blockIdx.y * 32, n0 = blockIdx.x * 32;
    const int lane = threadIdx.x;
    const int l15 = lane & 15, q = lane >> 4;
    const int rrow = lane >> 3, kof = (lane & 7) * 8;

    f32x4 acc[2][2];
    #pragma unroll
    for (int i = 0; i < 2; ++i)
        #pragma unroll
        for (int j = 0; j < 2; ++j) acc[i][j] = (f32x4){0.f, 0.f, 0.f, 0.f};

    for (int k0 = 0; k0 < K; k0 += 64) {
        #pragma unroll
        for (int r = 0; r < 4; ++r) {
            gld_lds16(A + (size_t)(m0 + r * 8 + rrow) * K + k0 + kof, As + r * 512);
            gld_lds16(B + (size_t)(n0 + r * 8 + rrow) * K + k0 + kof, Bs + r * 512);
        }
        __syncthreads();
        #pragma unroll
        for (int kk = 0; kk < 64; kk += 32) {
            f16x8 af[2], bf[2];
            #pragma unroll
            for (int i = 0; i < 2; ++i) af[i] = *(const f16x8*)(As + (i * 16 + l15) * 64 + kk + q * 8);
            #pragma unroll
            for (int j = 0; j < 2; ++j) bf[j] = *(const f16x8*)(Bs + (j * 16 + l15) * 64 + kk + q * 8);
            #pragma unroll
            for (int i = 0; i < 2; ++i)
                #pragma unroll
                for (int j = 0; j < 2; ++j)
                    acc[i][j] = __builtin_amdgcn_mfma_f32_16x16x32_f16(af[i], bf[j], acc[i][j], 0, 0, 0);
        }
        __syncthreads();
    }

    #pragma unroll
    for (int i = 0; i < 2; ++i) {
        #pragma unroll
        for (int rg = 0; rg < 4; ++rg) {
            int row = m0 + i * 16 + q * 4 + rg;
            #pragma unroll
            for (int j = 0; j < 2; ++j) {
                int col = n0 + j * 16 + l15;
                float z = acc[i][j][rg] + bias[col];
                float s = 1.f / (1.f + __expf(-z));
                if constexpr (EPI == 0) {
                    _Float16 h = (_Float16)s;
                    _Float16 lo = (_Float16)(s - (float)h);
                    _Float16* rp = o3 + (size_t)row * 1536;
                    rp[col] = h; rp[512 + col] = h; rp[1024 + col] = lo;
                    o2[(size_t)row * 512 + col] = s * (1.f - s);
                } else if constexpr (EPI == 1) {
                    o1[(size_t)row * 128 + col] = s;
                    o2[(size_t)row * 128 + col] = s * (1.f - s);
                    o3[(size_t)row * 128 + col] = (_Float16)s;
                } else {
                    o3[(size_t)row * 512 + col] = (_Float16)s;
                }
            }
        }
    }
}

// ---------------- build A_all[b][h][k] = f16(s2p[b][h]*W2[h][k]*s1p[b][k]) ----------------
__global__ __launch_bounds__(256) void build_A(const float* __restrict__ W2,
                                               const float* __restrict__ s1p,
                                               const float* __restrict__ s2p,
                                               _Float16* __restrict__ A_all) {
    const int b = blockIdx.x, tid = threadIdx.x;
    __shared__ float S1[512];
    __shared__ float S2[128];
    S1[tid]       = s1p[(size_t)b * 512 + tid];
    S1[tid + 256] = s1p[(size_t)b * 512 + tid + 256];
    if (tid < 128) S2[tid] = s2p[(size_t)b * 128 + tid];
    __syncthreads();
    _Float16* out = A_all + (size_t)b * 65536;
    #pragma unroll 4
    for (int i = 0; i < 32; ++i) {
        int c = tid + 256 * i;
        int h = c >> 6, k8 = (c & 63) * 8;
        f32x4 w0 = *(const f32x4*)(W2 + h * 512 + k8);
        f32x4 w1 = *(const f32x4*)(W2 + h * 512 + k8 + 4);
        float s2 = S2[h];
        f16x8 o;
        o[0] = (_Float16)(s2 * w0.x * S1[k8 + 0]);
        o[1] = (_Float16)(s2 * w0.y * S1[k8 + 1]);
        o[2] = (_Float16)(s2 * w0.z * S1[k8 + 2]);
        o[3] = (_Float16)(s2 * w0.w * S1[k8 + 3]);
        o[4] = (_Float16)(s2 * w1.x * S1[k8 + 4]);
        o[5] = (_Float16)(s2 * w1.y * S1[k8 + 5]);
        o[6] = (_Float16)(s2 * w1.z * S1[k8 + 6]);
        o[7] = (_Float16)(s2 * w1.w * S1[k8 + 7]);
        *(f16x8*)(out + h * 512 + k8) = o;
    }
}

// ---------------- recover: 128x128-tile MFMA GEMM (m97 pattern) ----------------
template <bool HAS_BIAS>
__global__ __launch_bounds__(256) void mfma_bt(const _Float16* __restrict__ A,
                                               const _Float16* __restrict__ Bmat,
                                               const float* __restrict__ bias,
                                               float* __restrict__ Out,
                                               int K, int N) {
    __shared__ __align__(16) _Float16 Asl[128 * 64];
    __shared__ __align__(16) _Float16 Bsl[128 * 64];
    __shared__ float Bias[128];
    const int m0 = blockIdx.y * 128, n0 = blockIdx.x * 128;
    const int tid = threadIdx.x;
    const int lane = tid & 63, wave = tid >> 6;
    const int wm = (wave >> 1) * 64, wn = (wave & 1) * 64;
    const int l15 = lane & 15, q = lane >> 4;

    if (HAS_BIAS && tid < 128) Bias[tid] = bias[n0 + tid];

    f32x4 acc[4][4];
    #pragma unroll
    for (int i = 0; i < 4; ++i)
        #pragma unroll
        for (int j = 0; j < 4; ++j) acc[i][j] = (f32x4){0.f, 0.f, 0.f, 0.f};

    const int rbase = wave * 8 + (lane >> 3);
    const int kof   = (lane & 7) * 8;

    for (int k0 = 0; k0 < K; k0 += 64) {
        #pragma unroll
        for (int r = 0; r < 4; ++r) {
            gld_lds16(A    + (size_t)(m0 + r * 32 + rbase) * K + k0 + kof, Asl + (r * 32 + wave * 8) * 64);
            gld_lds16(Bmat + (size_t)(n0 + r * 32 + rbase) * K + k0 + kof, Bsl + (r * 32 + wave * 8) * 64);
        }
        __syncthreads();
        #pragma unroll
        for (int kk = 0; kk < 64; kk += 32) {
            f16x8 af[4], bf[4];
            #pragma unroll
            for (int i = 0; i < 4; ++i)
                af[i] = *(const f16x8*)(Asl + (wm + i * 16 + l15) * 64 + kk + q * 8);
            #pragma unroll
            for (int j = 0; j < 4; ++j)
                bf[j] = *(const f16x8*)(Bsl + (wn + j * 16 + l15) * 64 + kk + q * 8);
            #pragma unroll
            for (int i = 0; i < 4; ++i)
                #pragma unroll
                for (int j = 0; j < 4; ++j)
                    acc[i][j] = __builtin_amdgcn_mfma_f32_16x16x32_f16(af[i], bf[j], acc[i][j], 0, 0, 0);
        }
        __syncthreads();
    }

    #pragma unroll
    for (int i = 0; i < 4; ++i) {
        #pragma unroll
        for (int rg = 0; rg < 4; ++rg) {
            int m = m0 + wm + i * 16 + q * 4 + rg;
            #pragma unroll
            for (int j = 0; j < 4; ++j) {
                int dcol = wn + j * 16 + l15;
                float v = acc[i][j][rg];
                if (HAS_BIAS) v += Bias[dcol];
                Out[(size_t)m * N + n0 + dcol] = v;
            }
        }
    }
}

// ---------------- jac256: 256x128 tile (2 batches/block), Out rows contiguous ----------------
__global__ __launch_bounds__(256) void jac256(const _Float16* __restrict__ A_all,  // [512][128][512]
                                              const _Float16* __restrict__ W1T,    // [1024][512]
                                              float* __restrict__ Jac) {           // [512*128][1024]
    __shared__ __align__(16) _Float16 Asl[256 * 64];  // 32 KB
    __shared__ __align__(16) _Float16 Bsl[128 * 64];  // 16 KB
    const int n0 = blockIdx.x * 128;
    const _Float16* A = A_all + (size_t)blockIdx.y * 131072;  // 2 batches, [256][512]
    float* Out = Jac + (size_t)blockIdx.y * 262144;           // [256][1024]
    const int tid = threadIdx.x;
    const int lane = tid & 63, wave = tid >> 6;
    const int wm = wave * 64;
    const int l15 = lane & 15, q = lane >> 4;
    const int rbase = wave * 8 + (lane >> 3);
    const int kof   = (lane & 7) * 8;

    f32x4 acc[4][8];
    #pragma unroll
    for (int i = 0; i < 4; ++i)
        #pragma unroll
        for (int j = 0; j < 8; ++j) acc[i][j] = (f32x4){0.f, 0.f, 0.f, 0.f};

    for (int k0 = 0; k0 < 512; k0 += 64) {
        #pragma unroll
        for (int r = 0; r < 8; ++r)
            gld_lds16(A + (size_t)(r * 32 + rbase) * 512 + k0 + kof, Asl + (r * 32 + wave * 8) * 64);
        #pragma unroll
        for (int r = 0; r < 4; ++r)
            gld_lds16(W1T + (size_t)(n0 + r * 32 + rbase) * 512 + k0 + kof, Bsl + (r * 32 + wave * 8) * 64);
        __syncthreads();
        #pragma unroll
        for (int kk = 0; kk < 64; kk += 32) {
            f16x8 af[4], bf[8];
            #pragma unroll
            for (int i = 0; i < 4; ++i)
                af[i] = *(const f16x8*)(Asl + (wm + i * 16 + l15) * 64 + kk + q * 8);
            #pragma unroll
            for (int j = 0; j < 8; ++j)
                bf[j] = *(const f16x8*)(Bsl + (j * 16 + l15) * 64 + kk + q * 8);
            #pragma unroll
            for (int i = 0; i < 4; ++i)
                #pragma unroll
                for (int j = 0; j < 8; ++j)
                    acc[i][j] = __builtin_amdgcn_mfma_f32_16x16x32_f16(af[i], bf[j], acc[i][j], 0, 0, 0);
        }
        __syncthreads();
    }

    #pragma unroll
    for (int i = 0; i < 4; ++i) {
        #pragma unroll
        for (int rg = 0; rg < 4; ++rg) {
            int m = wm + i * 16 + q * 4 + rg;
            #pragma unroll
            for (int j = 0; j < 8; ++j) {
                int d = n0 + j * 16 + l15;
                Out[(size_t)m * 1024 + d] = acc[i][j][rg];
            }
        }
    }
}

// ---------------- fallback fused Jacobian (only if ws too small for A_all) ----------------
__global__ __launch_bounds__(256) void jac_kernel(const _Float16* __restrict__ W2h,
                                                  const _Float16* __restrict__ W1T,
                                                  const float* __restrict__ s1p,
                                                  const float* __restrict__ s2p,
                                                  float* __restrict__ Jac) {
    __shared__ __align__(16) _Float16 Asl[128 * 64];
    __shared__ __align__(16) _Float16 Bsl[128 * 64];
    __shared__ float Ssl[128];
    const int b  = blockIdx.y;
    const int n0 = blockIdx.x * 128;
    const int tid = threadIdx.x;
    const int lane = tid & 63, wave = tid >> 6;
    const int wm = (wave >> 1) * 64, wn = (wave & 1) * 64;
    const int l15 = lane & 15, q = lane >> 4;

    if (tid < 128) Ssl[tid] = s2p[b * 128 + tid];

    f32x4 acc[4][4];
    #pragma unroll
    for (int i = 0; i < 4; ++i)
        #pragma unroll
        for (int j = 0; j < 4; ++j) acc[i][j] = (f32x4){0.f, 0.f, 0.f, 0.f};

    const int ah  = tid >> 4;
    const int akq = (tid & 15) * 4;
    const int rbase = wave * 8 + (lane >> 3);
    const int kof   = (lane & 7) * 8;

    for (int k0 = 0; k0 < 512; k0 += 64) {
        f32x4 s4 = *(const f32x4*)(s1p + (size_t)b * 512 + k0 + akq);
        f16x4 s4h;
        s4h.x = (_Float16)s4.x; s4h.y = (_Float16)s4.y;
        s4h.z = (_Float16)s4.z; s4h.w = (_Float16)s4.w;
        #pragma unroll
        for (int r = 0; r < 8; ++r) {
            int h = ah + r * 16;
            f16x4 w4 = *(const f16x4*)(W2h + (size_t)h * 512 + k0 + akq);
            *(f16x4*)(Asl + h * 64 + akq) = w4 * s4h;
        }
        #pragma unroll
        for (int r = 0; r < 4; ++r)
            gld_lds16(W1T + (size_t)(n0 + r * 32 + rbase) * 512 + k0 + kof,
                      Bsl + (r * 32 + wave * 8) * 64);
        __syncthreads();

        #pragma unroll
        for (int kk = 0; kk < 64; kk += 32) {
            f16x8 af[4], bf[4];
            #pragma unroll
            for (int i = 0; i < 4; ++i)
                af[i] = *(const f16x8*)(Asl + (wm + i * 16 + l15) * 64 + kk + q * 8);
            #pragma unroll
            for (int j = 0; j < 4; ++j)
                bf[j] = *(const f16x8*)(Bsl + (wn + j * 16 + l15) * 64 + kk + q * 8);
            #pragma unroll
            for (int i = 0; i < 4; ++i)
                #pragma unroll
                for (int j = 0; j < 4; ++j)
                    acc[i][j] = __builtin_amdgcn_mfma_f32_16x16x32_f16(af[i], bf[j], acc[i][j], 0, 0, 0);
        }
        __syncthreads();
    }

    float* outb = Jac + (size_t)b * (128 * 1024);
    #pragma unroll
    for (int i = 0; i < 4; ++i) {
        #pragma unroll
        for (int rg = 0; rg < 4; ++rg) {
            int h = wm + i * 16 + q * 4 + rg;
            float s = Ssl[h];
            #pragma unroll
            for (int j = 0; j < 4; ++j) {
                int d = n0 + wn + j * 16 + l15;
                outb[(size_t)h * 1024 + d] = acc[i][j][rg] * s;
            }
        }
    }
}

extern "C" void kernel_launch(void* const* d_in, const int* in_sizes, int n_in,
                              void* d_out, int out_size, void* d_ws, size_t ws_size,
                              hipStream_t stream) {
    const float* x  = (const float*)d_in[0];
    const float* W1 = (const float*)d_in[1];
    const float* b1 = (const float*)d_in[2];
    const float* W2 = (const float*)d_in[3];
    const float* b2 = (const float*)d_in[4];
    const float* b3 = (const float*)d_in[5];
    const float* br = (const float*)d_in[6];

    float* out_rec = (float*)d_out;               // 512*1024
    float* out_c2  = out_rec + 512 * 1024;        // 512*128
    float* out_jac = out_c2 + 512 * 128;          // 512*128*1024

    char* ws = (char*)d_ws;
    _Float16* W1T   = (_Float16*)(ws);             // 1 MB    [1024][512]
    _Float16* W2h   = (_Float16*)(ws + 0x100000);  // 128 KB  [128][512]
    _Float16* W2T_h = (_Float16*)(ws + 0x120000);  // 128 KB  [512][128]
    _Float16* c1s   = (_Float16*)(ws + 0x140000);  // 1.5 MB  [512][1536]
    float*    s1p   = (float*)   (ws + 0x2C0000);  // 1 MB
    float*    s2p   = (float*)   (ws + 0x3C0000);  // 256 KB
    _Float16* c2h   = (_Float16*)(ws + 0x400000);  // 128 KB  [512][128]
    _Float16* c3h   = (_Float16*)(ws + 0x420000);  // 512 KB  [512][512]
    _Float16* W1s   = (_Float16*)(ws + 0x4A0000);  // 3 MB    [512][3072]
    _Float16* xs    = (_Float16*)(ws + 0x7A0000);  // 3 MB    [512][3072]
    _Float16* W2s   = (_Float16*)(ws + 0xAA0000);  // 384 KB  [128][1536]
    _Float16* A_all = (_Float16*)(ws + 0xB00000);  // 64 MB   [512][128][512]
    const bool big_ws = ws_size >= (size_t)0x4B00000;

    prep_kernel<<<1728, 256, 0, stream>>>(W1, W2, x, W1T, W2h, W2T_h, W1s, xs, W2s);
    // c1 = sigmoid(x@W1^T+b1): split-f16 K=3072, M=N=512
    sgemm<0><<<dim3(16, 16), 64, 0, stream>>>(xs, W1s, b1, 3072, nullptr, s1p, c1s);
    // c2 = sigmoid(c1@W2^T+b2): split-f16 K=1536, M=512 N=128
    sgemm<1><<<dim3(4, 16), 64, 0, stream>>>(c1s, W2s, b2, 1536, out_c2, s2p, c2h);
    // c3 = sigmoid(c2@W2+b3): plain f16 K=128, M=N=512
    sgemm<2><<<dim3(16, 16), 64, 0, stream>>>(c2h, W2T_h, b3, 128, nullptr, nullptr, c3h);
    // recover = c3@W1 + br
    mfma_bt<true><<<dim3(8, 4), 256, 0, stream>>>(c3h, W1T, br, out_rec, 512, 1024);
    if (big_ws) {
        build_A<<<512, 256, 0, stream>>>(W2, s1p, s2p, A_all);
        jac256<<<dim3(8, 256), 256, 0, stream>>>(A_all, W1T, out_jac);
    } else {
        jac_kernel<<<dim3(8, 512), 256, 0, stream>>>(W2h, W1T, s1p, s2p, out_jac);
    }
}